// Round 1
// baseline (1856.526 us; speedup 1.0000x reference)
//
#include <hip/hip_runtime.h>

#define N_PTS   700000
#define N_VOXELS 250000
#define M_SP    20000
#define EPS_BN  1e-4f

// ---------------- voxelization: scatter mean ----------------
__global__ __launch_bounds__(256) void k_vox_scatter(const float* __restrict__ feats,
                                                     const int* __restrict__ p2v,
                                                     float* __restrict__ vox_sum,
                                                     float* __restrict__ vox_cnt) {
    int p = blockIdx.x * 256 + threadIdx.x;
    if (p >= N_PTS) return;
    int v = p2v[p];
    #pragma unroll
    for (int k = 0; k < 6; ++k)
        atomicAdd(&vox_sum[v * 6 + k], feats[p * 6 + k]);
    atomicAdd(&vox_cnt[v], 1.0f);
}

__global__ __launch_bounds__(256) void k_vox_div(float* __restrict__ vox,
                                                 const float* __restrict__ cnt) {
    int i = blockIdx.x * 256 + threadIdx.x;
    if (i >= N_VOXELS * 6) return;
    vox[i] = vox[i] / fmaxf(cnt[i / 6], 1.0f);
}

// ---------------- input conv 6->32 (+BN0+ReLU epilogue) ----------------
__global__ __launch_bounds__(256) void k_conv_in(const float* __restrict__ vox,
                                                 const int* __restrict__ nbr,
                                                 const float* __restrict__ W,
                                                 const float* __restrict__ gamma,
                                                 const float* __restrict__ beta,
                                                 float* __restrict__ x_out,
                                                 float* __restrict__ act_out) {
    __shared__ float w[27 * 6 * 32];
    for (int i = threadIdx.x; i < 27 * 6 * 32; i += 256) w[i] = W[i];
    __syncthreads();
    int g = threadIdx.x >> 5, c = threadIdx.x & 31;
    int v = blockIdx.x * 8 + g;
    if (v >= N_VOXELS) return;
    const int* nrow = nbr + (long)v * 27;
    float acc = 0.f;
    for (int o = 0; o < 27; ++o) {
        int n = nrow[o];
        if (n < 0) continue;
        const float* in = vox + (long)n * 6;
        #pragma unroll
        for (int k = 0; k < 6; ++k) acc += in[k] * w[(o * 6 + k) * 32 + c];
    }
    x_out[(long)v * 32 + c] = acc;
    float s = gamma[c] * rsqrtf(1.0f + EPS_BN);
    act_out[(long)v * 32 + c] = fmaxf(acc * s + beta[c], 0.0f);
}

// ---------------- 32->32 gather conv, register-tiled fp32 ----------------
// block = 128 voxels, 256 threads (4 waves x 32 voxels).
// lane tile: 4 voxels x 4 channels. LDS XOR-swizzled for conflict-free b128.
// epilogue: optional residual add into x_inout (writes back), then
// act_out = relu(bn(val)).
__global__ __launch_bounds__(256) void k_conv32(const float* __restrict__ act_in,
                                                const int* __restrict__ nbr,
                                                const float* __restrict__ W,
                                                const float* __restrict__ gamma,
                                                const float* __restrict__ beta,
                                                float* __restrict__ x_inout,
                                                float* __restrict__ act_out) {
    __shared__ float in_lds[128][32];
    __shared__ float wt_lds[32][32];
    __shared__ int nbr_lds[128 * 27];
    const int tid = threadIdx.x;
    const int vbase = blockIdx.x * 128;

    for (int i = tid; i < 128 * 27; i += 256) {
        long gi = (long)vbase * 27 + i;
        nbr_lds[i] = (gi < (long)N_VOXELS * 27) ? nbr[gi] : -1;
    }

    const int wav = tid >> 6;   // 0..3
    const int lane = tid & 63;
    const int vg = lane >> 3;   // 0..7  (voxel sub-row; r&7 == vg)
    const int cg = lane & 7;    // 0..7  (channel sub-col; c&7 == cg)

    float acc[4][4];
    #pragma unroll
    for (int a = 0; a < 4; ++a)
        #pragma unroll
        for (int b = 0; b < 4; ++b) acc[a][b] = 0.f;

    for (int o = 0; o < 27; ++o) {
        __syncthreads();   // prior iter's reads done before restage (also covers nbr_lds)
        // stage W_o transposed + swizzled: wt_lds[c][ ((k>>2)^(c&7))*4 + (k&3) ] = W[o][k][c]
        {
            int k = tid >> 3;
            int c4 = (tid & 7) * 4;
            float4 wv = *(const float4*)(W + (o * 32 + k) * 32 + c4);
            float wa[4] = {wv.x, wv.y, wv.z, wv.w};
            #pragma unroll
            for (int j = 0; j < 4; ++j) {
                int c = c4 + j;
                int cb = (k >> 2) ^ (c & 7);
                wt_lds[c][cb * 4 + (k & 3)] = wa[j];
            }
        }
        // stage gathered input rows swizzled: in_lds[row][ (seg^(row&7))*4 .. +3 ] = act[n][seg*4..+3]
        #pragma unroll
        for (int j = 0; j < 4; ++j) {
            int idx = tid * 4 + j;
            int row = idx >> 3;
            int seg = idx & 7;
            int n = nbr_lds[row * 27 + o];
            float4 val = make_float4(0.f, 0.f, 0.f, 0.f);
            if (n >= 0) val = *(const float4*)(act_in + (long)n * 32 + seg * 4);
            int cb = seg ^ (row & 7);
            *(float4*)&in_lds[row][cb * 4] = val;
        }
        __syncthreads();
        // compute: acc[vi][ci] += dot4(in[r][4k], w[4k][c]) over 8 k-steps
        #pragma unroll
        for (int ks = 0; ks < 8; ++ks) {
            float4 w4[4], i4[4];
            #pragma unroll
            for (int ci = 0; ci < 4; ++ci) {
                int c = ci * 8 + cg;
                w4[ci] = *(const float4*)&wt_lds[c][(ks ^ cg) << 2];
            }
            #pragma unroll
            for (int vi = 0; vi < 4; ++vi) {
                int r = wav * 32 + vi * 8 + vg;
                i4[vi] = *(const float4*)&in_lds[r][(ks ^ vg) << 2];
            }
            #pragma unroll
            for (int vi = 0; vi < 4; ++vi)
                #pragma unroll
                for (int ci = 0; ci < 4; ++ci)
                    acc[vi][ci] += i4[vi].x * w4[ci].x + i4[vi].y * w4[ci].y
                                 + i4[vi].z * w4[ci].z + i4[vi].w * w4[ci].w;
        }
    }

    float sc[4], bi[4];
    #pragma unroll
    for (int ci = 0; ci < 4; ++ci) {
        int c = ci * 8 + cg;
        sc[ci] = gamma[c] * rsqrtf(1.0f + EPS_BN);
        bi[ci] = beta[c];
    }
    #pragma unroll
    for (int vi = 0; vi < 4; ++vi) {
        int v = vbase + wav * 32 + vi * 8 + vg;
        if (v >= N_VOXELS) continue;
        #pragma unroll
        for (int ci = 0; ci < 4; ++ci) {
            int c = ci * 8 + cg;
            float val = acc[vi][ci];
            if (x_inout) {
                val += x_inout[(long)v * 32 + c];
                x_inout[(long)v * 32 + c] = val;
            }
            act_out[(long)v * 32 + c] = fmaxf(val * sc[ci] + bi[ci], 0.0f);
        }
    }
}

// ---------------- devoxelize + superpoint mean ----------------
__global__ __launch_bounds__(256) void k_devox(const float* __restrict__ act,
                                               const int* __restrict__ p2v,
                                               const int* __restrict__ sp,
                                               float* __restrict__ sp_sum,
                                               float* __restrict__ sp_cnt) {
    int grp = blockIdx.x * 8 + (threadIdx.x >> 5);
    int lane = threadIdx.x & 31;
    if (grp >= N_PTS) return;
    int v = p2v[grp];
    int s = sp[grp];
    atomicAdd(&sp_sum[(long)s * 32 + lane], act[(long)v * 32 + lane]);
    if (lane == 0) atomicAdd(&sp_cnt[s], 1.0f);
}

__global__ __launch_bounds__(256) void k_sp_div(const float* __restrict__ sp_sum,
                                                const float* __restrict__ sp_cnt,
                                                float* __restrict__ out) {
    int i = blockIdx.x * 256 + threadIdx.x;
    if (i >= M_SP * 32) return;
    out[i] = sp_sum[i] / fmaxf(sp_cnt[i >> 5], 1.0f);
}

extern "C" void kernel_launch(void* const* d_in, const int* in_sizes, int n_in,
                              void* d_out, int out_size, void* d_ws, size_t ws_size,
                              hipStream_t stream) {
    const float* feats    = (const float*)d_in[0];   // [700000,6]
    const float* W_in     = (const float*)d_in[1];   // [27,6,32]
    const float* W_blocks = (const float*)d_in[2];   // [2,2,27,32,32]
    const float* gamma    = (const float*)d_in[3];   // [5,32]
    const float* beta     = (const float*)d_in[4];   // [5,32]
    const int*   p2v      = (const int*)d_in[5];     // [700000]
    const int*   nbr      = (const int*)d_in[6];     // [250000,27]
    const int*   sp       = (const int*)d_in[7];     // [700000]
    float* out = (float*)d_out;                      // [20000,32]
    float* ws  = (float*)d_ws;

    // workspace layout (floats)
    float* vox_sum = ws;                         // N_VOXELS*6
    float* vox_cnt = ws + N_VOXELS * 6;          // N_VOXELS   (contiguous with vox_sum)
    float* x       = ws + 2000000;               // N_VOXELS*32
    float* actA    = ws + 10000000;              // N_VOXELS*32
    float* actB    = ws + 18000000;              // N_VOXELS*32
    float* sp_sum  = ws + 26000000;              // M_SP*32
    float* sp_cnt  = sp_sum + M_SP * 32;         // M_SP       (contiguous with sp_sum)

    hipMemsetAsync(vox_sum, 0, (size_t)N_VOXELS * 7 * sizeof(float), stream);
    hipMemsetAsync(sp_sum, 0, (size_t)M_SP * 33 * sizeof(float), stream);

    k_vox_scatter<<<(N_PTS + 255) / 256, 256, 0, stream>>>(feats, p2v, vox_sum, vox_cnt);
    k_vox_div<<<(N_VOXELS * 6 + 255) / 256, 256, 0, stream>>>(vox_sum, vox_cnt);

    // input conv + BN0 + ReLU
    k_conv_in<<<(N_VOXELS + 7) / 8, 256, 0, stream>>>(vox_sum, nbr, W_in,
                                                      gamma + 0, beta + 0, x, actA);

    const int CONV_GRID = (N_VOXELS + 127) / 128;
    const int WSZ = 27 * 32 * 32;  // floats per conv weight
    // block 0: conv(act0) -> act1 ; conv(act1)+x -> x, act2
    k_conv32<<<CONV_GRID, 256, 0, stream>>>(actA, nbr, W_blocks + 0 * WSZ,
                                            gamma + 32, beta + 32, nullptr, actB);
    k_conv32<<<CONV_GRID, 256, 0, stream>>>(actB, nbr, W_blocks + 1 * WSZ,
                                            gamma + 64, beta + 64, x, actA);
    // block 1
    k_conv32<<<CONV_GRID, 256, 0, stream>>>(actA, nbr, W_blocks + 2 * WSZ,
                                            gamma + 96, beta + 96, nullptr, actB);
    k_conv32<<<CONV_GRID, 256, 0, stream>>>(actB, nbr, W_blocks + 3 * WSZ,
                                            gamma + 128, beta + 128, x, actA);

    // devoxelize + superpoint mean
    k_devox<<<(N_PTS + 7) / 8, 256, 0, stream>>>(actA, p2v, sp, sp_sum, sp_cnt);
    k_sp_div<<<(M_SP * 32 + 255) / 256, 256, 0, stream>>>(sp_sum, sp_cnt, out);
}

// Round 2
// 807.965 us; speedup vs baseline: 2.2978x; 2.2978x over previous
//
#include <hip/hip_runtime.h>

#define N_PTS    700000
#define N_VOXELS 250000
#define M_SP     20000
#define EPS_BN   1e-4f

typedef __attribute__((ext_vector_type(8))) short  bf16x8;
typedef __attribute__((ext_vector_type(8))) ushort u16x8;
typedef __attribute__((ext_vector_type(4))) float  f32x4;

__device__ __forceinline__ ushort f2bf(float f) {
    unsigned u = __float_as_uint(f);
    return (ushort)((u + 0x7FFFu + ((u >> 16) & 1u)) >> 16);
}
__device__ __forceinline__ float bf2f(ushort h) {
    return __uint_as_float(((unsigned)h) << 16);
}

// ---------------- voxelization: scatter mean ----------------
__global__ __launch_bounds__(256) void k_vox_scatter(const float* __restrict__ feats,
                                                     const int* __restrict__ p2v,
                                                     float* __restrict__ vox_sum,
                                                     float* __restrict__ vox_cnt) {
    int p = blockIdx.x * 256 + threadIdx.x;
    if (p >= N_PTS) return;
    int v = p2v[p];
    #pragma unroll
    for (int k = 0; k < 6; ++k)
        atomicAdd(&vox_sum[v * 6 + k], feats[p * 6 + k]);
    atomicAdd(&vox_cnt[v], 1.0f);
}

__global__ __launch_bounds__(256) void k_vox_div(float* __restrict__ vox,
                                                 const float* __restrict__ cnt) {
    int i = blockIdx.x * 256 + threadIdx.x;
    if (i >= N_VOXELS * 6) return;
    vox[i] = vox[i] / fmaxf(cnt[i / 6], 1.0f);
}

// ---------------- input conv 6->32 (+BN0+ReLU epilogue) ----------------
__global__ __launch_bounds__(256) void k_conv_in(const float* __restrict__ vox,
                                                 const int* __restrict__ nbr,
                                                 const float* __restrict__ W,
                                                 const float* __restrict__ gamma,
                                                 const float* __restrict__ beta,
                                                 float* __restrict__ x_out,
                                                 ushort* __restrict__ act_out) {
    __shared__ float w[27 * 6 * 32];
    for (int i = threadIdx.x; i < 27 * 6 * 32; i += 256) w[i] = W[i];
    __syncthreads();
    int g = threadIdx.x >> 5, c = threadIdx.x & 31;
    int v = blockIdx.x * 8 + g;
    if (v >= N_VOXELS) return;
    const int* nrow = nbr + (size_t)v * 27;
    float acc = 0.f;
    for (int o = 0; o < 27; ++o) {
        int n = nrow[o];
        if (n < 0) continue;
        const float* in = vox + (size_t)n * 6;
        #pragma unroll
        for (int k = 0; k < 6; ++k) acc += in[k] * w[(o * 6 + k) * 32 + c];
    }
    x_out[(size_t)v * 32 + c] = acc;
    float s = gamma[c] * rsqrtf(1.0f + EPS_BN);
    act_out[(size_t)v * 32 + c] = f2bf(fmaxf(acc * s + beta[c], 0.0f));
}

// ---------------- weight pre-pack: fp32 [4][27][32k][32c] -> bf16 B-frag order ----
// Wb[conv][o][nf][lane][j] = W[conv][o][(lane>>4)*8 + j][nf*16 + (lane&15)]
__global__ __launch_bounds__(256) void k_wprep(const float* __restrict__ W,
                                               ushort* __restrict__ Wb) {
    int t = blockIdx.x * 256 + threadIdx.x;
    if (t >= 4 * 27 * 2 * 64) return;
    int l  = t & 63;
    int nf = (t >> 6) & 1;
    int co = t >> 7;                       // conv*27 + o
    const float* Wo = W + (size_t)co * 1024;
    int kb = (l >> 4) * 8;
    int c  = nf * 16 + (l & 15);
    u16x8 v;
    #pragma unroll
    for (int j = 0; j < 8; ++j) v[j] = f2bf(Wo[(kb + j) * 32 + c]);
    *(u16x8*)(Wb + (size_t)t * 8) = v;
}

// ---------------- 32->32 gather conv via bf16 MFMA ----------------
// block = 128 voxels, 4 waves; wave = 32 voxels (2 A-frags), N=32 (2 B-frags).
// A gathered straight from global (bf16 rows, 64B) into MFMA layout; no LDS
// staging of activations. nbr table staged in LDS (conflict-free [128][27]).
__global__ __launch_bounds__(256) void k_conv32m(const ushort* __restrict__ act_in,
                                                 const int* __restrict__ nbr,
                                                 const ushort* __restrict__ Wb,
                                                 const float* __restrict__ gamma,
                                                 const float* __restrict__ beta,
                                                 float* __restrict__ x_inout,
                                                 ushort* __restrict__ act_out) {
    __shared__ int nl[128][27];
    const int tid = threadIdx.x;
    const int vbase = blockIdx.x * 128;
    for (int i = tid; i < 128 * 27; i += 256) {
        int gi = vbase * 27 + i;                       // fits int: max 6.75M
        nl[0][i] = (gi < N_VOXELS * 27) ? nbr[gi] : -1;
    }
    __syncthreads();

    const int l   = tid & 63;
    const int wav = tid >> 6;
    const int r   = l & 15;     // A-row within frag / output channel (nf=0)
    const int g   = l >> 4;     // k-group for A/B; row-group for C/D
    const int vr0 = wav * 32 + r;
    const int vr1 = vr0 + 16;

    f32x4 a00 = {0,0,0,0}, a01 = {0,0,0,0}, a10 = {0,0,0,0}, a11 = {0,0,0,0};

    for (int o = 0; o < 27; ++o) {
        int n0 = nl[vr0][o];
        int n1 = nl[vr1][o];
        bf16x8 A0 = {0,0,0,0,0,0,0,0}, A1 = {0,0,0,0,0,0,0,0};
        if (n0 >= 0) A0 = *(const bf16x8*)(act_in + (size_t)n0 * 32 + g * 8);
        if (n1 >= 0) A1 = *(const bf16x8*)(act_in + (size_t)n1 * 32 + g * 8);
        const bf16x8 B0 = *(const bf16x8*)(Wb + (size_t)(o * 2 + 0) * 512 + l * 8);
        const bf16x8 B1 = *(const bf16x8*)(Wb + (size_t)(o * 2 + 1) * 512 + l * 8);
        a00 = __builtin_amdgcn_mfma_f32_16x16x32_bf16(A0, B0, a00, 0, 0, 0);
        a01 = __builtin_amdgcn_mfma_f32_16x16x32_bf16(A0, B1, a01, 0, 0, 0);
        a10 = __builtin_amdgcn_mfma_f32_16x16x32_bf16(A1, B0, a10, 0, 0, 0);
        a11 = __builtin_amdgcn_mfma_f32_16x16x32_bf16(A1, B1, a11, 0, 0, 0);
    }

    const float rs  = rsqrtf(1.f + EPS_BN);
    const float sc0 = gamma[r] * rs,      bb0 = beta[r];
    const float sc1 = gamma[r + 16] * rs, bb1 = beta[r + 16];

    // C/D layout: col = lane&15 (channel), row = (lane>>4)*4 + reg (voxel)
    #pragma unroll
    for (int fr = 0; fr < 2; ++fr) {
        #pragma unroll
        for (int j = 0; j < 4; ++j) {
            int vv = vbase + wav * 32 + fr * 16 + g * 4 + j;
            if (vv >= N_VOXELS) continue;
            float v0 = fr ? a10[j] : a00[j];
            float v1 = fr ? a11[j] : a01[j];
            if (x_inout) {
                float* xp = x_inout + (size_t)vv * 32;
                v0 += xp[r];
                v1 += xp[r + 16];
                xp[r]      = v0;
                xp[r + 16] = v1;
            }
            act_out[(size_t)vv * 32 + r]      = f2bf(fmaxf(v0 * sc0 + bb0, 0.f));
            act_out[(size_t)vv * 32 + r + 16] = f2bf(fmaxf(v1 * sc1 + bb1, 0.f));
        }
    }
}

// ---------------- devoxelize + superpoint mean ----------------
__global__ __launch_bounds__(256) void k_devox(const ushort* __restrict__ act,
                                               const int* __restrict__ p2v,
                                               const int* __restrict__ sp,
                                               float* __restrict__ sp_sum,
                                               float* __restrict__ sp_cnt) {
    int grp = blockIdx.x * 8 + (threadIdx.x >> 5);
    int lane = threadIdx.x & 31;
    if (grp >= N_PTS) return;
    int v = p2v[grp];
    int s = sp[grp];
    float val = bf2f(act[(size_t)v * 32 + lane]);
    atomicAdd(&sp_sum[(size_t)s * 32 + lane], val);
    if (lane == 0) atomicAdd(&sp_cnt[s], 1.0f);
}

__global__ __launch_bounds__(256) void k_sp_div(const float* __restrict__ sp_sum,
                                                const float* __restrict__ sp_cnt,
                                                float* __restrict__ out) {
    int i = blockIdx.x * 256 + threadIdx.x;
    if (i >= M_SP * 32) return;
    out[i] = sp_sum[i] / fmaxf(sp_cnt[i >> 5], 1.0f);
}

extern "C" void kernel_launch(void* const* d_in, const int* in_sizes, int n_in,
                              void* d_out, int out_size, void* d_ws, size_t ws_size,
                              hipStream_t stream) {
    const float* feats    = (const float*)d_in[0];   // [700000,6]
    const float* W_in     = (const float*)d_in[1];   // [27,6,32]
    const float* W_blocks = (const float*)d_in[2];   // [2,2,27,32,32]
    const float* gamma    = (const float*)d_in[3];   // [5,32]
    const float* beta     = (const float*)d_in[4];   // [5,32]
    const int*   p2v      = (const int*)d_in[5];     // [700000]
    const int*   nbr      = (const int*)d_in[6];     // [250000,27]
    const int*   sp       = (const int*)d_in[7];     // [700000]
    float* out = (float*)d_out;                      // [20000,32]
    float* wsf = (float*)d_ws;

    // workspace layout (float offsets)
    float*  vox_sum = wsf;                        // 1.5M floats
    float*  vox_cnt = wsf + 1500000;              // 0.25M (contiguous with vox_sum)
    float*  x       = wsf + 2000000;              // 8M
    float*  sp_sum  = wsf + 10000000;             // 640k
    float*  sp_cnt  = wsf + 10640000;             // 20k (contiguous with sp_sum)
    ushort* Wb      = (ushort*)(wsf + 11000000);  // 110592 ushorts
    ushort* actA    = (ushort*)(wsf + 12000000);  // 8M ushorts (bf16 [N_VOXELS,32])
    ushort* actB    = (ushort*)(wsf + 16000000);  // 8M ushorts

    hipMemsetAsync(vox_sum, 0, (size_t)N_VOXELS * 7 * sizeof(float), stream);
    hipMemsetAsync(sp_sum, 0, (size_t)M_SP * 33 * sizeof(float), stream);

    k_wprep<<<(4 * 27 * 2 * 64 + 255) / 256, 256, 0, stream>>>(W_blocks, Wb);

    k_vox_scatter<<<(N_PTS + 255) / 256, 256, 0, stream>>>(feats, p2v, vox_sum, vox_cnt);
    k_vox_div<<<(N_VOXELS * 6 + 255) / 256, 256, 0, stream>>>(vox_sum, vox_cnt);

    k_conv_in<<<(N_VOXELS + 7) / 8, 256, 0, stream>>>(vox_sum, nbr, W_in,
                                                      gamma + 0, beta + 0, x, actA);

    const int CONV_GRID = (N_VOXELS + 127) / 128;
    const int WBSZ = 27 * 2 * 64 * 8;   // ushorts per conv
    k_conv32m<<<CONV_GRID, 256, 0, stream>>>(actA, nbr, Wb + 0 * WBSZ,
                                             gamma + 32, beta + 32, nullptr, actB);
    k_conv32m<<<CONV_GRID, 256, 0, stream>>>(actB, nbr, Wb + 1 * WBSZ,
                                             gamma + 64, beta + 64, x, actA);
    k_conv32m<<<CONV_GRID, 256, 0, stream>>>(actA, nbr, Wb + 2 * WBSZ,
                                             gamma + 96, beta + 96, nullptr, actB);
    k_conv32m<<<CONV_GRID, 256, 0, stream>>>(actB, nbr, Wb + 3 * WBSZ,
                                             gamma + 128, beta + 128, x, actA);

    k_devox<<<(N_PTS + 7) / 8, 256, 0, stream>>>(actA, p2v, sp, sp_sum, sp_cnt);
    k_sp_div<<<(M_SP * 32 + 255) / 256, 256, 0, stream>>>(sp_sum, sp_cnt, out);
}

// Round 3
// 661.060 us; speedup vs baseline: 2.8084x; 1.2222x over previous
//
#include <hip/hip_runtime.h>

#define N_PTS    700000
#define N_VOXELS 250000
#define M_SP     20000
#define EPS_BN   1e-4f

typedef __attribute__((ext_vector_type(8))) short  bf16x8;
typedef __attribute__((ext_vector_type(8))) ushort u16x8;
typedef __attribute__((ext_vector_type(4))) float  f32x4;

__device__ __forceinline__ ushort f2bf(float f) {
    unsigned u = __float_as_uint(f);
    return (ushort)((u + 0x7FFFu + ((u >> 16) & 1u)) >> 16);
}
__device__ __forceinline__ float bf2f(ushort h) {
    return __uint_as_float(((unsigned)h) << 16);
}

// ================= CSR build (generic over segment map) =================
__global__ __launch_bounds__(256) void k_hist(const int* __restrict__ seg, int n,
                                              int* __restrict__ cnt) {
    int i = blockIdx.x * 256 + threadIdx.x;
    if (i < n) atomicAdd(&cnt[seg[i]], 1);
}

// per-1024-chunk partial sums
__global__ __launch_bounds__(256) void k_part(const int* __restrict__ cnt, int n,
                                              int* __restrict__ psum) {
    __shared__ int l[256];
    int b = blockIdx.x, t = threadIdx.x;
    int base = b * 1024 + t * 4;
    int s = 0;
    #pragma unroll
    for (int j = 0; j < 4; ++j) { int i = base + j; if (i < n) s += cnt[i]; }
    l[t] = s; __syncthreads();
    for (int st = 128; st > 0; st >>= 1) {
        if (t < st) l[t] += l[t + st];
        __syncthreads();
    }
    if (t == 0) psum[b] = l[0];
}

// single-block exclusive scan of psum (nb <= 256)
__global__ __launch_bounds__(256) void k_scan_psum(int* __restrict__ psum, int nb) {
    __shared__ int l[256];
    int t = threadIdx.x;
    int orig = (t < nb) ? psum[t] : 0;
    l[t] = orig; __syncthreads();
    for (int st = 1; st < 256; st <<= 1) {
        int v = (t >= st) ? l[t - st] : 0;
        __syncthreads();
        l[t] += v;
        __syncthreads();
    }
    if (t < nb) psum[t] = l[t] - orig;   // exclusive
}

// chunk-local exclusive scan + chunk base -> off[], cur[]
__global__ __launch_bounds__(256) void k_excl(const int* __restrict__ cnt,
                                              const int* __restrict__ psum, int n,
                                              int* __restrict__ off,
                                              int* __restrict__ cur) {
    __shared__ int l[256];
    int b = blockIdx.x, t = threadIdx.x;
    int base = b * 1024 + t * 4;
    int c[4]; int s = 0;
    #pragma unroll
    for (int j = 0; j < 4; ++j) {
        int i = base + j;
        c[j] = (i < n) ? cnt[i] : 0;
        s += c[j];
    }
    int orig = s;
    l[t] = s; __syncthreads();
    for (int st = 1; st < 256; st <<= 1) {
        int v = (t >= st) ? l[t - st] : 0;
        __syncthreads();
        l[t] += v;
        __syncthreads();
    }
    int run = l[t] - orig + psum[b];
    #pragma unroll
    for (int j = 0; j < 4; ++j) {
        int i = base + j;
        if (i < n) { off[i] = run; cur[i] = run; run += c[j]; }
    }
}

__global__ __launch_bounds__(256) void k_fill(const int* __restrict__ seg, int n,
                                              int* __restrict__ cur,
                                              int* __restrict__ pidx) {
    int i = blockIdx.x * 256 + threadIdx.x;
    if (i < n) {
        int pos = atomicAdd(&cur[seg[i]], 1);
        pidx[pos] = i;
    }
}

// ================= voxelization: CSR gather mean =================
__global__ __launch_bounds__(256) void k_vox_gather(const float* __restrict__ feats,
                                                    const int* __restrict__ off,
                                                    const int* __restrict__ cnt,
                                                    const int* __restrict__ pidx,
                                                    float* __restrict__ vox) {
    int v = blockIdx.x * 256 + threadIdx.x;
    if (v >= N_VOXELS) return;
    int s = off[v], c = cnt[v];
    float a0 = 0, a1 = 0, a2 = 0, a3 = 0, a4 = 0, a5 = 0;
    for (int k = 0; k < c; ++k) {
        int p = pidx[s + k];
        const float2* f = (const float2*)(feats + (size_t)p * 6);
        float2 x0 = f[0], x1 = f[1], x2 = f[2];
        a0 += x0.x; a1 += x0.y; a2 += x1.x; a3 += x1.y; a4 += x2.x; a5 += x2.y;
    }
    float inv = 1.0f / (float)max(c, 1);
    float* o = vox + (size_t)v * 6;
    o[0] = a0 * inv; o[1] = a1 * inv; o[2] = a2 * inv;
    o[3] = a3 * inv; o[4] = a4 * inv; o[5] = a5 * inv;
}

// ================= input conv 6->32 (+BN0+ReLU epilogue) =================
__global__ __launch_bounds__(256) void k_conv_in(const float* __restrict__ vox,
                                                 const int* __restrict__ nbr,
                                                 const float* __restrict__ W,
                                                 const float* __restrict__ gamma,
                                                 const float* __restrict__ beta,
                                                 float* __restrict__ x_out,
                                                 ushort* __restrict__ act_out) {
    __shared__ float w[27 * 6 * 32];
    for (int i = threadIdx.x; i < 27 * 6 * 32; i += 256) w[i] = W[i];
    __syncthreads();
    int g = threadIdx.x >> 5, c = threadIdx.x & 31;
    int v = blockIdx.x * 8 + g;
    if (v >= N_VOXELS) return;
    const int* nrow = nbr + (size_t)v * 27;
    float acc = 0.f;
    for (int o = 0; o < 27; ++o) {
        int n = nrow[o];
        if (n < 0) continue;
        const float* in = vox + (size_t)n * 6;
        #pragma unroll
        for (int k = 0; k < 6; ++k) acc += in[k] * w[(o * 6 + k) * 32 + c];
    }
    x_out[(size_t)v * 32 + c] = acc;
    float s = gamma[c] * rsqrtf(1.0f + EPS_BN);
    act_out[(size_t)v * 32 + c] = f2bf(fmaxf(acc * s + beta[c], 0.0f));
}

// ================= weight pre-pack to bf16 B-frag order =================
__global__ __launch_bounds__(256) void k_wprep(const float* __restrict__ W,
                                               ushort* __restrict__ Wb) {
    int t = blockIdx.x * 256 + threadIdx.x;
    if (t >= 4 * 27 * 2 * 64) return;
    int l  = t & 63;
    int nf = (t >> 6) & 1;
    int co = t >> 7;
    const float* Wo = W + (size_t)co * 1024;
    int kb = (l >> 4) * 8;
    int c  = nf * 16 + (l & 15);
    u16x8 v;
    #pragma unroll
    for (int j = 0; j < 8; ++j) v[j] = f2bf(Wo[(kb + j) * 32 + c]);
    *(u16x8*)(Wb + (size_t)t * 8) = v;
}

// ================= 32->32 gather conv via bf16 MFMA =================
__global__ __launch_bounds__(256) void k_conv32m(const ushort* __restrict__ act_in,
                                                 const int* __restrict__ nbr,
                                                 const ushort* __restrict__ Wb,
                                                 const float* __restrict__ gamma,
                                                 const float* __restrict__ beta,
                                                 float* __restrict__ x_inout,
                                                 ushort* __restrict__ act_out) {
    __shared__ int nl[128][27];
    const int tid = threadIdx.x;
    const int vbase = blockIdx.x * 128;
    for (int i = tid; i < 128 * 27; i += 256) {
        int gi = vbase * 27 + i;
        nl[0][i] = (gi < N_VOXELS * 27) ? nbr[gi] : -1;
    }
    __syncthreads();

    const int l   = tid & 63;
    const int wav = tid >> 6;
    const int r   = l & 15;
    const int g   = l >> 4;
    const int vr0 = wav * 32 + r;
    const int vr1 = vr0 + 16;

    f32x4 a00 = {0,0,0,0}, a01 = {0,0,0,0}, a10 = {0,0,0,0}, a11 = {0,0,0,0};

    for (int o = 0; o < 27; ++o) {
        int n0 = nl[vr0][o];
        int n1 = nl[vr1][o];
        bf16x8 A0 = {0,0,0,0,0,0,0,0}, A1 = {0,0,0,0,0,0,0,0};
        if (n0 >= 0) A0 = *(const bf16x8*)(act_in + (size_t)n0 * 32 + g * 8);
        if (n1 >= 0) A1 = *(const bf16x8*)(act_in + (size_t)n1 * 32 + g * 8);
        const bf16x8 B0 = *(const bf16x8*)(Wb + (size_t)(o * 2 + 0) * 512 + l * 8);
        const bf16x8 B1 = *(const bf16x8*)(Wb + (size_t)(o * 2 + 1) * 512 + l * 8);
        a00 = __builtin_amdgcn_mfma_f32_16x16x32_bf16(A0, B0, a00, 0, 0, 0);
        a01 = __builtin_amdgcn_mfma_f32_16x16x32_bf16(A0, B1, a01, 0, 0, 0);
        a10 = __builtin_amdgcn_mfma_f32_16x16x32_bf16(A1, B0, a10, 0, 0, 0);
        a11 = __builtin_amdgcn_mfma_f32_16x16x32_bf16(A1, B1, a11, 0, 0, 0);
    }

    const float rs  = rsqrtf(1.f + EPS_BN);
    const float sc0 = gamma[r] * rs,      bb0 = beta[r];
    const float sc1 = gamma[r + 16] * rs, bb1 = beta[r + 16];

    #pragma unroll
    for (int fr = 0; fr < 2; ++fr) {
        #pragma unroll
        for (int j = 0; j < 4; ++j) {
            int vv = vbase + wav * 32 + fr * 16 + g * 4 + j;
            if (vv >= N_VOXELS) continue;
            float v0 = fr ? a10[j] : a00[j];
            float v1 = fr ? a11[j] : a01[j];
            if (x_inout) {
                float* xp = x_inout + (size_t)vv * 32;
                v0 += xp[r];
                v1 += xp[r + 16];
                xp[r]      = v0;
                xp[r + 16] = v1;
            }
            act_out[(size_t)vv * 32 + r]      = f2bf(fmaxf(v0 * sc0 + bb0, 0.f));
            act_out[(size_t)vv * 32 + r + 16] = f2bf(fmaxf(v1 * sc1 + bb1, 0.f));
        }
    }
}

// ================= superpoint mean: CSR gather (wave per superpoint) =================
__global__ __launch_bounds__(256) void k_sp_gather(const ushort* __restrict__ act,
                                                   const int* __restrict__ p2v,
                                                   const int* __restrict__ off,
                                                   const int* __restrict__ cnt,
                                                   const int* __restrict__ pidx,
                                                   float* __restrict__ out) {
    int sp = blockIdx.x * 4 + (threadIdx.x >> 6);
    if (sp >= M_SP) return;
    int l   = threadIdx.x & 63;
    int grp = l >> 4;          // 4 points in parallel
    int ch2 = l & 15;          // 2 channels per lane
    int s = off[sp], c = cnt[sp];
    float a0 = 0.f, a1 = 0.f;
    for (int j = s + grp; j < s + c; j += 4) {
        int p = pidx[j];
        int v = p2v[p];
        unsigned pk = *(const unsigned*)(act + (size_t)v * 32 + ch2 * 2);
        a0 += __uint_as_float(pk << 16);
        a1 += __uint_as_float(pk & 0xFFFF0000u);
    }
    a0 += __shfl_xor(a0, 16); a1 += __shfl_xor(a1, 16);
    a0 += __shfl_xor(a0, 32); a1 += __shfl_xor(a1, 32);
    if (grp == 0) {
        float inv = 1.0f / (float)max(c, 1);
        *(float2*)(out + (size_t)sp * 32 + ch2 * 2) = make_float2(a0 * inv, a1 * inv);
    }
}

extern "C" void kernel_launch(void* const* d_in, const int* in_sizes, int n_in,
                              void* d_out, int out_size, void* d_ws, size_t ws_size,
                              hipStream_t stream) {
    const float* feats    = (const float*)d_in[0];
    const float* W_in     = (const float*)d_in[1];
    const float* W_blocks = (const float*)d_in[2];
    const float* gamma    = (const float*)d_in[3];
    const float* beta     = (const float*)d_in[4];
    const int*   p2v      = (const int*)d_in[5];
    const int*   nbr      = (const int*)d_in[6];
    const int*   sp       = (const int*)d_in[7];
    float* out = (float*)d_out;
    float* wsf = (float*)d_ws;

    // ---- workspace layout (float offsets) ----
    float*  vox    = wsf;                          // 1.5M
    int*    cnt_v  = (int*)(wsf + 1500000);        // 250k
    int*    off_v  = (int*)(wsf + 1750000);        // 250k
    int*    cur_v  = (int*)(wsf + 2000000);        // 250k
    int*    psum_v = (int*)(wsf + 2250000);        // 245
    int*    pidx_v = (int*)(wsf + 2300000);        // 700k
    float*  x      = wsf + 3000000;                // 8M
    int*    cnt_s  = (int*)(wsf + 11000000);       // 20k
    int*    off_s  = (int*)(wsf + 11050000);       // 20k
    int*    cur_s  = (int*)(wsf + 11100000);       // 20k
    int*    psum_s = (int*)(wsf + 11150000);       // 20
    int*    pidx_s = (int*)(wsf + 11200000);       // 700k
    ushort* Wb     = (ushort*)(wsf + 12000000);    // 110592 ushorts
    ushort* actA   = (ushort*)(wsf + 12100000);    // 8M ushorts
    ushort* actB   = (ushort*)(wsf + 16200000);    // 8M ushorts

    const int NB_V = (N_VOXELS + 1023) / 1024;     // 245 (<=256)
    const int NB_S = (M_SP + 1023) / 1024;         // 20  (<=256)
    const int GP   = (N_PTS + 255) / 256;

    hipMemsetAsync(cnt_v, 0, N_VOXELS * sizeof(int), stream);
    hipMemsetAsync(cnt_s, 0, M_SP * sizeof(int), stream);

    k_wprep<<<(4 * 27 * 2 * 64 + 255) / 256, 256, 0, stream>>>(W_blocks, Wb);

    // ---- CSR for p2v ----
    k_hist<<<GP, 256, 0, stream>>>(p2v, N_PTS, cnt_v);
    k_part<<<NB_V, 256, 0, stream>>>(cnt_v, N_VOXELS, psum_v);
    k_scan_psum<<<1, 256, 0, stream>>>(psum_v, NB_V);
    k_excl<<<NB_V, 256, 0, stream>>>(cnt_v, psum_v, N_VOXELS, off_v, cur_v);
    k_fill<<<GP, 256, 0, stream>>>(p2v, N_PTS, cur_v, pidx_v);

    // ---- CSR for superpoints ----
    k_hist<<<GP, 256, 0, stream>>>(sp, N_PTS, cnt_s);
    k_part<<<NB_S, 256, 0, stream>>>(cnt_s, M_SP, psum_s);
    k_scan_psum<<<1, 256, 0, stream>>>(psum_s, NB_S);
    k_excl<<<NB_S, 256, 0, stream>>>(cnt_s, psum_s, M_SP, off_s, cur_s);
    k_fill<<<GP, 256, 0, stream>>>(sp, N_PTS, cur_s, pidx_s);

    // ---- voxelization (gather mean) ----
    k_vox_gather<<<(N_VOXELS + 255) / 256, 256, 0, stream>>>(feats, off_v, cnt_v,
                                                             pidx_v, vox);

    // ---- input conv ----
    k_conv_in<<<(N_VOXELS + 7) / 8, 256, 0, stream>>>(vox, nbr, W_in,
                                                      gamma + 0, beta + 0, x, actA);

    // ---- residual blocks ----
    const int CONV_GRID = (N_VOXELS + 127) / 128;
    const int WBSZ = 27 * 2 * 64 * 8;
    k_conv32m<<<CONV_GRID, 256, 0, stream>>>(actA, nbr, Wb + 0 * WBSZ,
                                             gamma + 32, beta + 32, nullptr, actB);
    k_conv32m<<<CONV_GRID, 256, 0, stream>>>(actB, nbr, Wb + 1 * WBSZ,
                                             gamma + 64, beta + 64, x, actA);
    k_conv32m<<<CONV_GRID, 256, 0, stream>>>(actA, nbr, Wb + 2 * WBSZ,
                                             gamma + 96, beta + 96, nullptr, actB);
    k_conv32m<<<CONV_GRID, 256, 0, stream>>>(actB, nbr, Wb + 3 * WBSZ,
                                             gamma + 128, beta + 128, x, actA);

    // ---- superpoint mean (gather) ----
    k_sp_gather<<<(M_SP + 3) / 4, 256, 0, stream>>>(actA, p2v, off_s, cnt_s,
                                                    pidx_s, out);
}

// Round 6
// 519.210 us; speedup vs baseline: 3.5757x; 1.2732x over previous
//
#include <hip/hip_runtime.h>

#define N_PTS    700000
#define N_VOXELS 250000
#define M_SP     20000
#define EPS_BN   1e-4f

typedef __attribute__((ext_vector_type(8))) short  bf16x8;
typedef __attribute__((ext_vector_type(8))) ushort u16x8;
typedef __attribute__((ext_vector_type(4))) float  f32x4;

__device__ __forceinline__ ushort f2bf(float f) {
    unsigned u = __float_as_uint(f);
    return (ushort)((u + 0x7FFFu + ((u >> 16) & 1u)) >> 16);
}
__device__ __forceinline__ float bf2f(ushort h) {
    return __uint_as_float(((unsigned)h) << 16);
}

// ================= CSR build (both segmentations in one sweep) =================
__global__ __launch_bounds__(256) void k_hist2(const int* __restrict__ p2v,
                                               const int* __restrict__ sp,
                                               int* __restrict__ cnt_v,
                                               int* __restrict__ cnt_s) {
    int i = blockIdx.x * 256 + threadIdx.x;
    if (i < N_PTS) {
        atomicAdd(&cnt_v[p2v[i]], 1);
        atomicAdd(&cnt_s[sp[i]], 1);
    }
}

__global__ __launch_bounds__(256) void k_part(const int* __restrict__ cnt, int n,
                                              int* __restrict__ psum) {
    __shared__ int l[256];
    int b = blockIdx.x, t = threadIdx.x;
    int base = b * 1024 + t * 4;
    int s = 0;
    #pragma unroll
    for (int j = 0; j < 4; ++j) { int i = base + j; if (i < n) s += cnt[i]; }
    l[t] = s; __syncthreads();
    for (int st = 128; st > 0; st >>= 1) {
        if (t < st) l[t] += l[t + st];
        __syncthreads();
    }
    if (t == 0) psum[b] = l[0];
}

__global__ __launch_bounds__(256) void k_scan_psum(int* __restrict__ psum, int nb) {
    __shared__ int l[256];
    int t = threadIdx.x;
    int orig = (t < nb) ? psum[t] : 0;
    l[t] = orig; __syncthreads();
    for (int st = 1; st < 256; st <<= 1) {
        int v = (t >= st) ? l[t - st] : 0;
        __syncthreads();
        l[t] += v;
        __syncthreads();
    }
    if (t < nb) psum[t] = l[t] - orig;
}

__global__ __launch_bounds__(256) void k_excl(const int* __restrict__ cnt,
                                              const int* __restrict__ psum, int n,
                                              int* __restrict__ off,
                                              int* __restrict__ cur) {
    __shared__ int l[256];
    int b = blockIdx.x, t = threadIdx.x;
    int base = b * 1024 + t * 4;
    int c[4]; int s = 0;
    #pragma unroll
    for (int j = 0; j < 4; ++j) {
        int i = base + j;
        c[j] = (i < n) ? cnt[i] : 0;
        s += c[j];
    }
    int orig = s;
    l[t] = s; __syncthreads();
    for (int st = 1; st < 256; st <<= 1) {
        int v = (t >= st) ? l[t - st] : 0;
        __syncthreads();
        l[t] += v;
        __syncthreads();
    }
    int run = l[t] - orig + psum[b];
    #pragma unroll
    for (int j = 0; j < 4; ++j) {
        int i = base + j;
        if (i < n) { off[i] = run; cur[i] = run; run += c[j]; }
    }
}

__global__ __launch_bounds__(256) void k_fill2(const int* __restrict__ p2v,
                                               const int* __restrict__ sp,
                                               int* __restrict__ cur_v,
                                               int* __restrict__ cur_s,
                                               int* __restrict__ pidx_v,
                                               int* __restrict__ pidx_s) {
    int i = blockIdx.x * 256 + threadIdx.x;
    if (i < N_PTS) {
        pidx_v[atomicAdd(&cur_v[p2v[i]], 1)] = i;
        pidx_s[atomicAdd(&cur_s[sp[i]], 1)] = i;
    }
}

// ================= voxelization: CSR gather mean -> bf16 hi/lo (8ch padded) =================
__global__ __launch_bounds__(256) void k_vox_gather(const float* __restrict__ feats,
                                                    const int* __restrict__ off,
                                                    const int* __restrict__ cnt,
                                                    const int* __restrict__ pidx,
                                                    ushort* __restrict__ voxH,
                                                    ushort* __restrict__ voxL) {
    int v = blockIdx.x * 256 + threadIdx.x;
    if (v >= N_VOXELS) return;
    int s = off[v], c = cnt[v];
    float a[6] = {0, 0, 0, 0, 0, 0};
    for (int k = 0; k < c; ++k) {
        int p = pidx[s + k];
        const float2* f = (const float2*)(feats + (size_t)p * 6);
        float2 x0 = f[0], x1 = f[1], x2 = f[2];
        a[0] += x0.x; a[1] += x0.y; a[2] += x1.x;
        a[3] += x1.y; a[4] += x2.x; a[5] += x2.y;
    }
    float inv = 1.0f / (float)max(c, 1);
    u16x8 hv, lv;
    #pragma unroll
    for (int j = 0; j < 6; ++j) {
        float m = a[j] * inv;
        ushort h = f2bf(m);
        hv[j] = h;
        lv[j] = f2bf(m - bf2f(h));
    }
    hv[6] = 0; hv[7] = 0; lv[6] = 0; lv[7] = 0;
    *(u16x8*)(voxH + (size_t)v * 8) = hv;
    *(u16x8*)(voxL + (size_t)v * 8) = lv;
}

// ================= weight pre-pack: conv_in (hi/lo), K = 4 offsets x 8 ch =================
// WbH/L[(s7*2+nf)*512 + l*8 + j]: k=(l>>4)*8+j <-> (offset s7*4+(l>>4), ch j)
__global__ __launch_bounds__(256) void k_wprep_in(const float* __restrict__ W,
                                                  ushort* __restrict__ WbH,
                                                  ushort* __restrict__ WbL) {
    int t = blockIdx.x * 256 + threadIdx.x;
    if (t >= 7 * 2 * 64) return;
    int l  = t & 63;
    int nf = (t >> 6) & 1;
    int s7 = t >> 7;
    int g  = l >> 4;
    int c  = nf * 16 + (l & 15);
    int o  = s7 * 4 + g;
    u16x8 hv, lv;
    #pragma unroll
    for (int j = 0; j < 8; ++j) {
        float w = (j < 6 && o < 27) ? W[(o * 6 + j) * 32 + c] : 0.0f;
        ushort h = f2bf(w);
        hv[j] = h;
        lv[j] = f2bf(w - bf2f(h));
    }
    *(u16x8*)(WbH + (size_t)t * 8) = hv;
    *(u16x8*)(WbL + (size_t)t * 8) = lv;
}

// ================= weight pre-pack: conv32m bf16 B-frag order =================
__global__ __launch_bounds__(256) void k_wprep(const float* __restrict__ W,
                                               ushort* __restrict__ Wb) {
    int t = blockIdx.x * 256 + threadIdx.x;
    if (t >= 4 * 27 * 2 * 64) return;
    int l  = t & 63;
    int nf = (t >> 6) & 1;
    int co = t >> 7;
    const float* Wo = W + (size_t)co * 1024;
    int kb = (l >> 4) * 8;
    int c  = nf * 16 + (l & 15);
    u16x8 v;
    #pragma unroll
    for (int j = 0; j < 8; ++j) v[j] = f2bf(Wo[(kb + j) * 32 + c]);
    *(u16x8*)(Wb + (size_t)t * 8) = v;
}

// ================= input conv 6->32 via MFMA (hi/lo split, ~fp32 accurate) =================
__global__ __launch_bounds__(256) void k_conv_in_m(const ushort* __restrict__ voxH,
                                                   const ushort* __restrict__ voxL,
                                                   const int* __restrict__ nbr,
                                                   const ushort* __restrict__ WbH,
                                                   const ushort* __restrict__ WbL,
                                                   const float* __restrict__ gamma,
                                                   const float* __restrict__ beta,
                                                   float* __restrict__ x_out,
                                                   ushort* __restrict__ act_out) {
    __shared__ int nl[128][27];
    const int tid = threadIdx.x;
    const int vbase = blockIdx.x * 128;
    for (int i = tid; i < 128 * 27; i += 256) {
        int gi = vbase * 27 + i;
        nl[0][i] = (gi < N_VOXELS * 27) ? nbr[gi] : -1;
    }
    __syncthreads();

    const int l   = tid & 63;
    const int wav = tid >> 6;
    const int r   = l & 15;
    const int g   = l >> 4;
    const int vr0 = wav * 32 + r;
    const int vr1 = vr0 + 16;

    f32x4 a00 = {0,0,0,0}, a01 = {0,0,0,0}, a10 = {0,0,0,0}, a11 = {0,0,0,0};

    for (int s7 = 0; s7 < 7; ++s7) {
        int o = s7 * 4 + g;
        int n0 = (o < 27) ? nl[vr0][o] : -1;
        int n1 = (o < 27) ? nl[vr1][o] : -1;
        bf16x8 A0h = {0,0,0,0,0,0,0,0}, A0l = {0,0,0,0,0,0,0,0};
        bf16x8 A1h = {0,0,0,0,0,0,0,0}, A1l = {0,0,0,0,0,0,0,0};
        if (n0 >= 0) {
            A0h = *(const bf16x8*)(voxH + (size_t)n0 * 8);
            A0l = *(const bf16x8*)(voxL + (size_t)n0 * 8);
        }
        if (n1 >= 0) {
            A1h = *(const bf16x8*)(voxH + (size_t)n1 * 8);
            A1l = *(const bf16x8*)(voxL + (size_t)n1 * 8);
        }
        const bf16x8 B0h = *(const bf16x8*)(WbH + (size_t)(s7 * 2 + 0) * 512 + l * 8);
        const bf16x8 B1h = *(const bf16x8*)(WbH + (size_t)(s7 * 2 + 1) * 512 + l * 8);
        const bf16x8 B0l = *(const bf16x8*)(WbL + (size_t)(s7 * 2 + 0) * 512 + l * 8);
        const bf16x8 B1l = *(const bf16x8*)(WbL + (size_t)(s7 * 2 + 1) * 512 + l * 8);
        // (Ah+Al)*Bh + Ah*Bl  ==  A*B to ~2^-17
        a00 = __builtin_amdgcn_mfma_f32_16x16x32_bf16(A0h, B0h, a00, 0, 0, 0);
        a00 = __builtin_amdgcn_mfma_f32_16x16x32_bf16(A0l, B0h, a00, 0, 0, 0);
        a00 = __builtin_amdgcn_mfma_f32_16x16x32_bf16(A0h, B0l, a00, 0, 0, 0);
        a01 = __builtin_amdgcn_mfma_f32_16x16x32_bf16(A0h, B1h, a01, 0, 0, 0);
        a01 = __builtin_amdgcn_mfma_f32_16x16x32_bf16(A0l, B1h, a01, 0, 0, 0);
        a01 = __builtin_amdgcn_mfma_f32_16x16x32_bf16(A0h, B1l, a01, 0, 0, 0);
        a10 = __builtin_amdgcn_mfma_f32_16x16x32_bf16(A1h, B0h, a10, 0, 0, 0);
        a10 = __builtin_amdgcn_mfma_f32_16x16x32_bf16(A1l, B0h, a10, 0, 0, 0);
        a10 = __builtin_amdgcn_mfma_f32_16x16x32_bf16(A1h, B0l, a10, 0, 0, 0);
        a11 = __builtin_amdgcn_mfma_f32_16x16x32_bf16(A1h, B1h, a11, 0, 0, 0);
        a11 = __builtin_amdgcn_mfma_f32_16x16x32_bf16(A1l, B1h, a11, 0, 0, 0);
        a11 = __builtin_amdgcn_mfma_f32_16x16x32_bf16(A1h, B1l, a11, 0, 0, 0);
    }

    const float rs  = rsqrtf(1.f + EPS_BN);
    const float sc0 = gamma[r] * rs,      bb0 = beta[r];
    const float sc1 = gamma[r + 16] * rs, bb1 = beta[r + 16];

    #pragma unroll
    for (int fr = 0; fr < 2; ++fr) {
        #pragma unroll
        for (int j = 0; j < 4; ++j) {
            int vv = vbase + wav * 32 + fr * 16 + g * 4 + j;
            if (vv >= N_VOXELS) continue;
            float v0 = fr ? a10[j] : a00[j];
            float v1 = fr ? a11[j] : a01[j];
            float* xp = x_out + (size_t)vv * 32;
            xp[r]      = v0;
            xp[r + 16] = v1;
            act_out[(size_t)vv * 32 + r]      = f2bf(fmaxf(v0 * sc0 + bb0, 0.f));
            act_out[(size_t)vv * 32 + r + 16] = f2bf(fmaxf(v1 * sc1 + bb1, 0.f));
        }
    }
}

// ================= 32->32 gather conv via bf16 MFMA =================
__global__ __launch_bounds__(256) void k_conv32m(const ushort* __restrict__ act_in,
                                                 const int* __restrict__ nbr,
                                                 const ushort* __restrict__ Wb,
                                                 const float* __restrict__ gamma,
                                                 const float* __restrict__ beta,
                                                 float* __restrict__ x_inout,
                                                 ushort* __restrict__ act_out) {
    __shared__ int nl[128][27];
    const int tid = threadIdx.x;
    const int vbase = blockIdx.x * 128;
    for (int i = tid; i < 128 * 27; i += 256) {
        int gi = vbase * 27 + i;
        nl[0][i] = (gi < N_VOXELS * 27) ? nbr[gi] : -1;
    }
    __syncthreads();

    const int l   = tid & 63;
    const int wav = tid >> 6;
    const int r   = l & 15;
    const int g   = l >> 4;
    const int vr0 = wav * 32 + r;
    const int vr1 = vr0 + 16;

    f32x4 a00 = {0,0,0,0}, a01 = {0,0,0,0}, a10 = {0,0,0,0}, a11 = {0,0,0,0};

    for (int o = 0; o < 27; ++o) {
        int n0 = nl[vr0][o];
        int n1 = nl[vr1][o];
        bf16x8 A0 = {0,0,0,0,0,0,0,0}, A1 = {0,0,0,0,0,0,0,0};
        if (n0 >= 0) A0 = *(const bf16x8*)(act_in + (size_t)n0 * 32 + g * 8);
        if (n1 >= 0) A1 = *(const bf16x8*)(act_in + (size_t)n1 * 32 + g * 8);
        const bf16x8 B0 = *(const bf16x8*)(Wb + (size_t)(o * 2 + 0) * 512 + l * 8);
        const bf16x8 B1 = *(const bf16x8*)(Wb + (size_t)(o * 2 + 1) * 512 + l * 8);
        a00 = __builtin_amdgcn_mfma_f32_16x16x32_bf16(A0, B0, a00, 0, 0, 0);
        a01 = __builtin_amdgcn_mfma_f32_16x16x32_bf16(A0, B1, a01, 0, 0, 0);
        a10 = __builtin_amdgcn_mfma_f32_16x16x32_bf16(A1, B0, a10, 0, 0, 0);
        a11 = __builtin_amdgcn_mfma_f32_16x16x32_bf16(A1, B1, a11, 0, 0, 0);
    }

    const float rs  = rsqrtf(1.f + EPS_BN);
    const float sc0 = gamma[r] * rs,      bb0 = beta[r];
    const float sc1 = gamma[r + 16] * rs, bb1 = beta[r + 16];

    #pragma unroll
    for (int fr = 0; fr < 2; ++fr) {
        #pragma unroll
        for (int j = 0; j < 4; ++j) {
            int vv = vbase + wav * 32 + fr * 16 + g * 4 + j;
            if (vv >= N_VOXELS) continue;
            float v0 = fr ? a10[j] : a00[j];
            float v1 = fr ? a11[j] : a01[j];
            if (x_inout) {
                float* xp = x_inout + (size_t)vv * 32;
                v0 += xp[r];
                v1 += xp[r + 16];
                xp[r]      = v0;
                xp[r + 16] = v1;
            }
            act_out[(size_t)vv * 32 + r]      = f2bf(fmaxf(v0 * sc0 + bb0, 0.f));
            act_out[(size_t)vv * 32 + r + 16] = f2bf(fmaxf(v1 * sc1 + bb1, 0.f));
        }
    }
}

// ================= superpoint mean: CSR gather (wave per superpoint) =================
__global__ __launch_bounds__(256) void k_sp_gather(const ushort* __restrict__ act,
                                                   const int* __restrict__ p2v,
                                                   const int* __restrict__ off,
                                                   const int* __restrict__ cnt,
                                                   const int* __restrict__ pidx,
                                                   float* __restrict__ out) {
    int sp = blockIdx.x * 4 + (threadIdx.x >> 6);
    if (sp >= M_SP) return;
    int l   = threadIdx.x & 63;
    int grp = l >> 4;
    int ch2 = l & 15;
    int s = off[sp], c = cnt[sp];
    float a0 = 0.f, a1 = 0.f;
    for (int j = s + grp; j < s + c; j += 4) {
        int p = pidx[j];
        int v = p2v[p];
        unsigned pk = *(const unsigned*)(act + (size_t)v * 32 + ch2 * 2);
        a0 += __uint_as_float(pk << 16);
        a1 += __uint_as_float(pk & 0xFFFF0000u);
    }
    a0 += __shfl_xor(a0, 16); a1 += __shfl_xor(a1, 16);
    a0 += __shfl_xor(a0, 32); a1 += __shfl_xor(a1, 32);
    if (grp == 0) {
        float inv = 1.0f / (float)max(c, 1);
        *(float2*)(out + (size_t)sp * 32 + ch2 * 2) = make_float2(a0 * inv, a1 * inv);
    }
}

extern "C" void kernel_launch(void* const* d_in, const int* in_sizes, int n_in,
                              void* d_out, int out_size, void* d_ws, size_t ws_size,
                              hipStream_t stream) {
    const float* feats    = (const float*)d_in[0];
    const float* W_in     = (const float*)d_in[1];
    const float* W_blocks = (const float*)d_in[2];
    const float* gamma    = (const float*)d_in[3];
    const float* beta     = (const float*)d_in[4];
    const int*   p2v      = (const int*)d_in[5];
    const int*   nbr      = (const int*)d_in[6];
    const int*   sp       = (const int*)d_in[7];
    float* out = (float*)d_out;
    float* wsf = (float*)d_ws;

    // ---- workspace layout (float offsets), total ~20.0M floats ----
    int*    cnt_v  = (int*)(wsf + 0);              // 250k
    int*    off_v  = (int*)(wsf + 250000);         // 250k
    int*    cnt_s  = (int*)(wsf + 500000);         // 20k
    int*    off_s  = (int*)(wsf + 520000);         // 20k
    int*    psum_v = (int*)(wsf + 540000);         // 256
    int*    psum_s = (int*)(wsf + 541000);         // 256
    int*    pidx_v = (int*)(wsf + 542000);         // 700k
    int*    pidx_s = (int*)(wsf + 1242000);        // 700k
    ushort* voxH   = (ushort*)(wsf + 1942000);     // 2M ush (1M f)
    ushort* voxL   = (ushort*)(wsf + 2942000);     // 2M ush
    ushort* WbH_in = (ushort*)(wsf + 3942000);     // 7168 ush
    ushort* WbL_in = (ushort*)(wsf + 3946000);     // 7168 ush
    ushort* Wb     = (ushort*)(wsf + 3950000);     // 110592 ush
    float*  x      = wsf + 4006000;                // 8M
    ushort* actA   = (ushort*)(wsf + 12006000);    // 8M ush
    ushort* actB   = (ushort*)(wsf + 16006000);    // 8M ush
    // cur_* alias voxH region (dead before k_vox_gather writes voxH)
    int*    cur_v  = (int*)(wsf + 1942000);        // 250k
    int*    cur_s  = (int*)(wsf + 2192000);        // 20k

    const int NB_V = (N_VOXELS + 1023) / 1024;     // 245
    const int NB_S = (M_SP + 1023) / 1024;         // 20
    const int GP   = (N_PTS + 255) / 256;

    hipMemsetAsync(cnt_v, 0, N_VOXELS * sizeof(int), stream);
    hipMemsetAsync(cnt_s, 0, M_SP * sizeof(int), stream);

    k_wprep<<<(4 * 27 * 2 * 64 + 255) / 256, 256, 0, stream>>>(W_blocks, Wb);
    k_wprep_in<<<(7 * 2 * 64 + 255) / 256, 256, 0, stream>>>(W_in, WbH_in, WbL_in);

    // ---- CSR build (fused) ----
    k_hist2<<<GP, 256, 0, stream>>>(p2v, sp, cnt_v, cnt_s);
    k_part<<<NB_V, 256, 0, stream>>>(cnt_v, N_VOXELS, psum_v);
    k_part<<<NB_S, 256, 0, stream>>>(cnt_s, M_SP, psum_s);
    k_scan_psum<<<1, 256, 0, stream>>>(psum_v, NB_V);
    k_scan_psum<<<1, 256, 0, stream>>>(psum_s, NB_S);
    k_excl<<<NB_V, 256, 0, stream>>>(cnt_v, psum_v, N_VOXELS, off_v, cur_v);
    k_excl<<<NB_S, 256, 0, stream>>>(cnt_s, psum_s, M_SP, off_s, cur_s);
    k_fill2<<<GP, 256, 0, stream>>>(p2v, sp, cur_v, cur_s, pidx_v, pidx_s);

    // ---- voxelization (gather mean -> bf16 hi/lo) ----
    k_vox_gather<<<(N_VOXELS + 255) / 256, 256, 0, stream>>>(feats, off_v, cnt_v,
                                                             pidx_v, voxH, voxL);

    // ---- input conv (MFMA, hi/lo ~fp32) ----
    const int CONV_GRID = (N_VOXELS + 127) / 128;
    k_conv_in_m<<<CONV_GRID, 256, 0, stream>>>(voxH, voxL, nbr, WbH_in, WbL_in,
                                               gamma + 0, beta + 0, x, actA);

    // ---- residual blocks ----
    const int WBSZ = 27 * 2 * 64 * 8;
    k_conv32m<<<CONV_GRID, 256, 0, stream>>>(actA, nbr, Wb + 0 * WBSZ,
                                             gamma + 32, beta + 32, nullptr, actB);
    k_conv32m<<<CONV_GRID, 256, 0, stream>>>(actB, nbr, Wb + 1 * WBSZ,
                                             gamma + 64, beta + 64, x, actA);
    k_conv32m<<<CONV_GRID, 256, 0, stream>>>(actA, nbr, Wb + 2 * WBSZ,
                                             gamma + 96, beta + 96, nullptr, actB);
    k_conv32m<<<CONV_GRID, 256, 0, stream>>>(actB, nbr, Wb + 3 * WBSZ,
                                             gamma + 128, beta + 128, x, actA);

    // ---- superpoint mean (gather) ----
    k_sp_gather<<<(M_SP + 3) / 4, 256, 0, stream>>>(actA, p2v, off_s, cnt_s,
                                                    pidx_s, out);
}